// Round 6
// baseline (630.755 us; speedup 1.0000x reference)
//
#include <hip/hip_runtime.h>
#include <math.h>

// SuperVoxel critical-component loss on MI355X.
// mean( (0.5 + 0.25*neg + 0.25*pos) * bce_loss )
// Run-based CCL with DENSE run ids (prefix-scanned per row) and XCD-confined
// processing: image img is handled only by blocks with blockIdx&7 == img&7,
// so each XCD's ~2 images of parent state (~3.9MB) stay resident in its
// private 4MB L2. Union-find pointer chases and CAS traffic never leave L2.

#define HH 1024
#define WW 1024
#define IMGPIX (HH * WW)
#define NB_TOTAL 16
#define FLAGBIT 0x40000000
#define IDXMASK 0x3FFFFFFF
#define NBLK 2048
#define NTHR 256
#define WPR 16                 // u64 mask words per row
#define MAXRUNS_PI (HH * 512)  // worst-case run slots per image per phase

typedef unsigned long long u64;

__device__ __forceinline__ int findRootG(const int* __restrict__ p, int i) {
    int r = i;
    int pr = p[r] & IDXMASK;
    while (pr != r) { r = pr; pr = p[r] & IDXMASK; }
    return r;
}

__device__ __forceinline__ void uniteG(int* p, int a, int b) {
    int ra = findRootG(p, a), rb = findRootG(p, b);
    while (ra != rb) {
        if (ra < rb) { int t = ra; ra = rb; rb = t; }  // hook larger under smaller
        int prev = atomicCAS(&p[ra], ra, rb);
        if (prev == ra) return;
        ra = findRootG(p, prev & IDXMASK);
        rb = findRootG(p, rb);
    }
}

// index (within row) of the run containing bit b of this word; requires fg@b.
__device__ __forceinline__ int runIndexW(u64 starts, int b) {
    u64 below = (2ULL << b) - 1ULL;  // b=63 wraps to ~0ULL
    return (int)__popcll(starts & below) - 1;
}

__global__ void k_zero(double* __restrict__ part) {
    part[blockIdx.x * blockDim.x + threadIdx.x] = 0.0;
}

// Ballot fg masks for both phases.
__global__ void k_mask(const float* __restrict__ preds, const float* __restrict__ targets,
                       long gbase, int npx, u64* __restrict__ fT, u64* __restrict__ fP) {
    int stride = gridDim.x * blockDim.x;
    for (int i = blockIdx.x * blockDim.x + threadIdx.x; i < npx; i += stride) {
        float p = preds[gbase + i];
        float t = targets[gbase + i];
        u64 bp = __ballot(p > 0.5f);
        u64 bt = __ballot(t > 0.0f);
        if ((i & 63) == 0) { fP[i >> 6] = bp; fT[i >> 6] = bt; }
    }
}

// Per row: run-start masks (carry-aware), per-word prefix, per-row run count.
__global__ void k_rows(const u64* __restrict__ fT, const u64* __restrict__ fP,
                       u64* __restrict__ sT, u64* __restrict__ sP,
                       int* __restrict__ prT, int* __restrict__ prP,
                       int* __restrict__ rcT, int* __restrict__ rcP, int nrows) {
    int R = blockIdx.x * blockDim.x + threadIdx.x;
    if (R >= nrows) return;
    for (int ph = 0; ph < 2; ++ph) {
        const u64* f = ph ? fP : fT;
        u64* s = ph ? sP : sT;
        int* pr = ph ? prP : prT;
        int* rc = ph ? rcP : rcT;
        int cum = 0;
        u64 carry = 0;
        #pragma unroll
        for (int w = 0; w < WPR; ++w) {
            u64 fw = f[R * WPR + w];
            u64 st = fw & ~((fw << 1) | carry);
            carry = fw >> 63;
            s[R * WPR + w] = st;
            pr[R * WPR + w] = cum;
            cum += (int)__popcll(st);
        }
        rc[R] = cum;
    }
}

// Exclusive scan of row counts -> dense row bases; meta[ph] = grand total.
__global__ void k_scan(const int* __restrict__ rcT, const int* __restrict__ rcP,
                       int* __restrict__ rbT, int* __restrict__ rbP,
                       int* __restrict__ meta, int nrows) {
    __shared__ int sums[NTHR];
    int per = (nrows + NTHR - 1) / NTHR;
    for (int ph = 0; ph < 2; ++ph) {
        const int* rc = ph ? rcP : rcT;
        int* rb = ph ? rbP : rbT;
        int st = threadIdx.x * per;
        int s = 0;
        for (int j = 0; j < per; ++j) { int r = st + j; if (r < nrows) s += rc[r]; }
        sums[threadIdx.x] = s;
        __syncthreads();
        if (threadIdx.x == 0) {
            int acc = 0;
            for (int i = 0; i < NTHR; ++i) { int t = sums[i]; sums[i] = acc; acc += t; }
            meta[ph] = acc;
        }
        __syncthreads();
        int run = sums[threadIdx.x];
        for (int j = 0; j < per; ++j) {
            int r = st + j;
            if (r < nrows) { rb[r] = run; run += rc[r]; }
        }
        __syncthreads();
    }
}

// XCD-confined parent init over each image's dense run range.
__global__ void k_initp(const int* __restrict__ rbT, const int* __restrict__ rbP,
                        const int* __restrict__ meta,
                        int* __restrict__ parentT, int* __restrict__ parentP, int nb) {
    int xcd = blockIdx.x & 7, gid = blockIdx.x >> 3;
    int ngrp = gridDim.x >> 3;
    for (int img = xcd; img < nb; img += 8) {
        for (int ph = 0; ph < 2; ++ph) {
            const int* rb = ph ? rbP : rbT;
            int* parent = ph ? parentP : parentT;
            int base = rb[img * HH];
            int end = (img == nb - 1) ? meta[ph] : rb[(img + 1) * HH];
            for (int i = base + gid * NTHR + threadIdx.x; i < end; i += ngrp * NTHR)
                parent[i] = i;
        }
    }
}

// XCD-confined vertical linking: one unite per overlap-run between row pairs.
__global__ void k_link(const u64* __restrict__ fT, const u64* __restrict__ fP,
                       const u64* __restrict__ sT, const u64* __restrict__ sP,
                       const int* __restrict__ prT, const int* __restrict__ prP,
                       const int* __restrict__ rbT, const int* __restrict__ rbP,
                       int* __restrict__ parentT, int* __restrict__ parentP, int nb) {
    int xcd = blockIdx.x & 7, gid = blockIdx.x >> 3;
    int ngrp = gridDim.x >> 3;
    const int per = (HH - 1) * WPR;
    for (int img = xcd; img < nb; img += 8) {
        for (int it = gid * NTHR + threadIdx.x; it < 2 * per; it += ngrp * NTHR) {
            int ph = it >= per;
            int rem = ph ? it - per : it;
            int r = rem >> 4, w = rem & 15;
            int R = img * HH + r;
            const u64* f = ph ? fP : fT;
            const u64* s = ph ? sP : sT;
            const int* pr = ph ? prP : prT;
            const int* rb = ph ? rbP : rbT;
            int* parent = ph ? parentP : parentT;
            int w0 = R * WPR + w, w1 = w0 + WPR;
            u64 f0 = f[w0], f1 = f[w1];
            u64 o = f0 & f1;
            if (!o) continue;
            u64 s0 = s[w0], s1 = s[w1];
            int b0 = rb[R] + pr[w0], b1 = rb[R + 1] + pr[w1];
            u64 os = o & ~(o << 1);  // one unite per overlap-run
            while (os) {
                int b = __builtin_ctzll(os);
                os &= os - 1;
                uniteG(parent, b0 + runIndexW(s0, b), b1 + runIndexW(s1, b));
            }
        }
    }
}

// XCD-confined: flag the root of every run containing a mistake pixel.
__global__ void k_flagup(const u64* __restrict__ fT, const u64* __restrict__ fP,
                         const u64* __restrict__ sT, const u64* __restrict__ sP,
                         const int* __restrict__ prT, const int* __restrict__ prP,
                         const int* __restrict__ rbT, const int* __restrict__ rbP,
                         int* __restrict__ parentT, int* __restrict__ parentP, int nb) {
    int xcd = blockIdx.x & 7, gid = blockIdx.x >> 3;
    int ngrp = gridDim.x >> 3;
    const int per = HH * WPR;
    for (int img = xcd; img < nb; img += 8) {
        for (int it = gid * NTHR + threadIdx.x; it < 2 * per; it += ngrp * NTHR) {
            int ph = it >= per;
            int rem = ph ? it - per : it;
            int widx = img * HH * WPR + rem;
            const u64* fA = ph ? fP : fT;
            const u64* fB = ph ? fT : fP;
            u64 m = fA[widx] & ~fB[widx];
            if (!m) continue;
            const u64* s = ph ? sP : sT;
            const int* pr = ph ? prP : prT;
            const int* rb = ph ? rbP : rbT;
            int* parent = ph ? parentP : parentT;
            int R = img * HH + (rem >> 4);
            int base = rb[R] + pr[widx];
            u64 sw = s[widx];
            u64 ms = m & ~(m << 1);
            int last = -1;
            while (ms) {
                int b = __builtin_ctzll(ms);
                ms &= ms - 1;
                int rid = base + runIndexW(sw, b);
                if (rid != last) {
                    last = rid;
                    int rt = findRootG(parent, rid);
                    if (!(parent[rt] & FLAGBIT)) atomicOr(&parent[rt], FLAGBIT);
                }
            }
        }
    }
}

// XCD-confined: every run entry -> root | rootflag (1-hop lookups in accum).
__global__ void k_compress(const int* __restrict__ rbT, const int* __restrict__ rbP,
                           const int* __restrict__ meta,
                           int* __restrict__ parentT, int* __restrict__ parentP, int nb) {
    int xcd = blockIdx.x & 7, gid = blockIdx.x >> 3;
    int ngrp = gridDim.x >> 3;
    for (int img = xcd; img < nb; img += 8) {
        for (int ph = 0; ph < 2; ++ph) {
            const int* rb = ph ? rbP : rbT;
            int* parent = ph ? parentP : parentT;
            int base = rb[img * HH];
            int end = (img == nb - 1) ? meta[ph] : rb[(img + 1) * HH];
            for (int i = base + gid * NTHR + threadIdx.x; i < end; i += ngrp * NTHR) {
                int r = findRootG(parent, i);
                parent[i] = r | (parent[r] & FLAGBIT);
            }
        }
    }
}

// XCD-confined fused loss + weights; crit lookup once per run segment.
__global__ void k_accum(const float* __restrict__ preds, const float* __restrict__ targets,
                        long gbase,
                        const u64* __restrict__ fT, const u64* __restrict__ fP,
                        const u64* __restrict__ sT, const u64* __restrict__ sP,
                        const int* __restrict__ prT, const int* __restrict__ prP,
                        const int* __restrict__ rbT, const int* __restrict__ rbP,
                        const int* __restrict__ parentT, const int* __restrict__ parentP,
                        double* __restrict__ part, int nb) {
    int xcd = blockIdx.x & 7, gid = blockIdx.x >> 3;
    int ngrp = gridDim.x >> 3;
    double local = 0.0;
    for (int img = xcd; img < nb; img += 8) {
        const float4* p4 = (const float4*)(preds + gbase + (long)img * IMGPIX);
        const float4* t4 = (const float4*)(targets + gbase + (long)img * IMGPIX);
        for (int i = gid * NTHR + threadIdx.x; i < IMGPIX / 4; i += ngrp * NTHR) {
            int px = i << 2;                       // pixel index within image
            int R = img * HH + (px >> 10);
            int wi = R * WPR + ((px >> 6) & 15);   // word index within chunk
            float4 pv = p4[i];
            float4 tv = t4[i];
            u64 ft = fT[wi], fp = fP[wi];
            u64 st = sT[wi], sp = sP[wi];
            int baseT = rbT[R] + prT[wi];
            int baseP = rbP[R] + prP[wi];
            float pa[4] = {pv.x, pv.y, pv.z, pv.w};
            float ta[4] = {tv.x, tv.y, tv.z, tv.w};
            int lastT = -1, lastP = -1;
            float flagT = 0.0f, flagP = 0.0f;
            #pragma unroll
            for (int j = 0; j < 4; ++j) {
                int b = (px & 63) + j;
                float p = pa[j], t = ta[j];
                float loss = fmaxf(p, 0.0f) - p * t + log1pf(__expf(-fabsf(p)));
                float wgt = 0.5f;
                if ((ft >> b) & 1) {
                    int rid = baseT + runIndexW(st, b);
                    if (rid != lastT) { lastT = rid; flagT = (parentT[rid] & FLAGBIT) ? 0.25f : 0.0f; }
                    wgt += flagT;
                }
                if ((fp >> b) & 1) {
                    int rid = baseP + runIndexW(sp, b);
                    if (rid != lastP) { lastP = rid; flagP = (parentP[rid] & FLAGBIT) ? 0.25f : 0.0f; }
                    wgt += flagP;
                }
                local += (double)(wgt * loss);
            }
        }
    }
    #pragma unroll
    for (int off = 32; off > 0; off >>= 1) local += __shfl_down(local, off, 64);
    __shared__ double sh[NTHR / 64];
    int lane = threadIdx.x & 63, wid = threadIdx.x >> 6;
    if (lane == 0) sh[wid] = local;
    __syncthreads();
    if (threadIdx.x == 0) {
        double tot = 0.0;
        #pragma unroll
        for (int w = 0; w < NTHR / 64; ++w) tot += sh[w];
        part[blockIdx.x] += tot;  // zeroed each launch; chunks accumulate serially
    }
}

__global__ void k_final(const double* __restrict__ part, float* __restrict__ out, double inv_n) {
    double v = 0.0;
    for (int i = threadIdx.x; i < NBLK; i += blockDim.x) v += part[i];
    #pragma unroll
    for (int off = 32; off > 0; off >>= 1) v += __shfl_down(v, off, 64);
    __shared__ double sh[NTHR / 64];
    int lane = threadIdx.x & 63, wid = threadIdx.x >> 6;
    if (lane == 0) sh[wid] = v;
    __syncthreads();
    if (threadIdx.x == 0) {
        double tot = 0.0;
        #pragma unroll
        for (int w = 0; w < NTHR / 64; ++w) tot += sh[w];
        out[0] = (float)(tot * inv_n);
    }
}

extern "C" void kernel_launch(void* const* d_in, const int* in_sizes, int n_in,
                              void* d_out, int out_size, void* d_ws, size_t ws_size,
                              hipStream_t stream) {
    const float* preds = (const float*)d_in[0];
    const float* targets = (const float*)d_in[1];
    float* out = (float*)d_out;

    // ws: part | meta | fT fP sT sP | prT prP | rcT rcP rbT rbP | parentT parentP
    double* part = (double*)d_ws;
    int* meta = (int*)((char*)d_ws + NBLK * sizeof(double));
    char* base = (char*)d_ws + NBLK * sizeof(double) + 256;
    size_t avail = ((char*)d_ws + ws_size > base) ? (size_t)((char*)d_ws + ws_size - base) : 0;
    const size_t wpi = (size_t)HH * WPR;  // 16384 words per image
    const size_t per_img = 4 * wpi * sizeof(u64) + 2 * wpi * sizeof(int)
                         + 4 * HH * sizeof(int) + 2 * (size_t)MAXRUNS_PI * sizeof(int);
    int chunk = (int)(avail / per_img);
    if (chunk < 1) chunk = 1;
    if (chunk > NB_TOTAL) chunk = NB_TOTAL;

    u64* fT = (u64*)base;
    u64* fP = fT + (size_t)chunk * wpi;
    u64* sT = fP + (size_t)chunk * wpi;
    u64* sP = sT + (size_t)chunk * wpi;
    int* prT = (int*)(sP + (size_t)chunk * wpi);
    int* prP = prT + (size_t)chunk * wpi;
    int* rcT = prP + (size_t)chunk * wpi;
    int* rcP = rcT + (size_t)chunk * HH;
    int* rbT = rcP + (size_t)chunk * HH;
    int* rbP = rbT + (size_t)chunk * HH;
    int* parentT = rbP + (size_t)chunk * HH;
    int* parentP = parentT + (size_t)chunk * MAXRUNS_PI;

    k_zero<<<NBLK / NTHR, NTHR, 0, stream>>>(part);

    for (int b0 = 0; b0 < NB_TOTAL; b0 += chunk) {
        int nb = (b0 + chunk <= NB_TOTAL) ? chunk : (NB_TOTAL - b0);
        int npx = nb * IMGPIX;
        long gbase = (long)b0 * IMGPIX;
        int nrows = nb * HH;

        k_mask<<<NBLK, NTHR, 0, stream>>>(preds, targets, gbase, npx, fT, fP);
        k_rows<<<(nrows + NTHR - 1) / NTHR, NTHR, 0, stream>>>(fT, fP, sT, sP, prT, prP,
                                                               rcT, rcP, nrows);
        k_scan<<<1, NTHR, 0, stream>>>(rcT, rcP, rbT, rbP, meta, nrows);
        k_initp<<<NBLK, NTHR, 0, stream>>>(rbT, rbP, meta, parentT, parentP, nb);
        k_link<<<NBLK, NTHR, 0, stream>>>(fT, fP, sT, sP, prT, prP, rbT, rbP,
                                          parentT, parentP, nb);
        k_flagup<<<NBLK, NTHR, 0, stream>>>(fT, fP, sT, sP, prT, prP, rbT, rbP,
                                            parentT, parentP, nb);
        k_compress<<<NBLK, NTHR, 0, stream>>>(rbT, rbP, meta, parentT, parentP, nb);
        k_accum<<<NBLK, NTHR, 0, stream>>>(preds, targets, gbase, fT, fP, sT, sP,
                                           prT, prP, rbT, rbP, parentT, parentP, part, nb);
    }

    double inv_n = 1.0 / ((double)NB_TOTAL * (double)IMGPIX);
    k_final<<<1, NTHR, 0, stream>>>(part, out, inv_n);
}

// Round 7
// 315.215 us; speedup vs baseline: 2.0010x; 2.0010x over previous
//
#include <hip/hip_runtime.h>
#include <math.h>

// SuperVoxel critical-component loss on MI355X.
// mean( (0.5 + 0.25*neg + 0.25*pos) * bce_loss )
// Run-based CCL, two-level: ALL intra-strip (32 rows) unions + mistake flags
// happen in LDS (worst-case 16384 run slots = 64KB); global CAS only on the
// 31 strip seams per image (~250K unites total, 18x fewer than round 6).
// Flag-carrying global union-find keeps component flags valid across seams.
// Streaming compress folds root|flag into every entry; accum is 1-hop.

#define HH 1024
#define WW 1024
#define IMGPIX (HH * WW)
#define NB_TOTAL 16
#define FLAGBIT 0x40000000
#define IDXMASK 0x3FFFFFFF
#define NBLK 2048
#define NTHR 256
#define WPR 16               // u64 mask words per row
#define RPR 512              // run slots per row (hard worst case)
#define SROWS 32             // rows per strip
#define STRIPS (HH / SROWS)  // 32 strips per image
#define SLOTS (SROWS * RPR)  // 16384 slots per strip
#define NTHR_S 1024

typedef unsigned long long u64;

// ---------- global union-find (flag-aware) ----------
__device__ __forceinline__ int findRootG(const int* __restrict__ p, int i) {
    int r = i;
    int pr = p[r] & IDXMASK;
    while (pr != r) { r = pr; pr = p[r] & IDXMASK; }
    return r;
}

// Propagate FLAG to the current root of x's tree (loops if root got hooked).
__device__ __forceinline__ void flagProp(int* p, int x) {
    while (true) {
        int r = findRootG(p, x);
        int old = atomicOr(&p[r], FLAGBIT);
        if ((old & IDXMASK) == r) return;  // was a root when OR landed
        x = old & IDXMASK;
    }
}

// Unite with flag carrying: hooking a flagged root propagates its flag.
__device__ __forceinline__ void uniteGF(int* p, int a, int b) {
    int ra = findRootG(p, a), rb = findRootG(p, b);
    while (ra != rb) {
        if (ra < rb) { int t = ra; ra = rb; rb = t; }  // hook larger under smaller
        int e = p[ra];
        if ((e & IDXMASK) != ra) { ra = findRootG(p, e & IDXMASK); continue; }
        int prev = atomicCAS(&p[ra], e, rb);
        if (prev == e) {
            if (e & FLAGBIT) flagProp(p, rb);
            return;
        }
        ra = findRootG(p, prev & IDXMASK);
        rb = findRootG(p, rb);
    }
}

// ---------- LDS union-find (flags appear only after unite phase) ----------
__device__ __forceinline__ int findRootL(volatile int* lab, int i) {
    int r = i;
    int e = lab[r] & IDXMASK;
    while (e != r) { r = e; e = lab[r] & IDXMASK; }
    return r;
}

__device__ __forceinline__ void uniteL(int* lab, int a, int b) {
    volatile int* vl = lab;
    int ra = findRootL(vl, a), rb = findRootL(vl, b);
    while (ra != rb) {
        if (ra < rb) { int t = ra; ra = rb; rb = t; }
        int prev = atomicCAS(&lab[ra], ra, rb);
        if (prev == ra) return;
        ra = findRootL(vl, prev & IDXMASK);
        rb = findRootL(vl, rb);
    }
}

// index (within row) of the run containing bit b of this word; requires fg@b.
__device__ __forceinline__ int runIndexW(u64 starts, int b) {
    u64 below = (2ULL << b) - 1ULL;  // b=63 wraps to ~0ULL
    return (int)__popcll(starts & below) - 1;
}

__global__ void k_zero(double* __restrict__ part) {
    part[blockIdx.x * blockDim.x + threadIdx.x] = 0.0;
}

// Ballot fg masks for both phases.
__global__ void k_mask(const float* __restrict__ preds, const float* __restrict__ targets,
                       long gbase, int npx, u64* __restrict__ fT, u64* __restrict__ fP) {
    int stride = gridDim.x * blockDim.x;
    for (int i = blockIdx.x * blockDim.x + threadIdx.x; i < npx; i += stride) {
        float p = preds[gbase + i];
        float t = targets[gbase + i];
        u64 bp = __ballot(p > 0.5f);
        u64 bt = __ballot(t > 0.0f);
        if ((i & 63) == 0) { fP[i >> 6] = bp; fT[i >> 6] = bt; }
    }
}

// Per (row,phase): run-start masks (carry-aware) + per-word prefix counts.
__global__ void k_rows(const u64* __restrict__ fT, const u64* __restrict__ fP,
                       u64* __restrict__ sT, u64* __restrict__ sP,
                       int* __restrict__ prT, int* __restrict__ prP, int nrows) {
    int id = blockIdx.x * blockDim.x + threadIdx.x;
    if (id >= 2 * nrows) return;
    int ph = id >= nrows;
    int R = ph ? id - nrows : id;
    const u64* f = ph ? fP : fT;
    u64* s = ph ? sP : sT;
    int* pr = ph ? prP : prT;
    int cum = 0;
    u64 carry = 0;
    #pragma unroll
    for (int w = 0; w < WPR; ++w) {
        u64 fw = f[R * WPR + w];
        u64 st = fw & ~((fw << 1) | carry);
        carry = fw >> 63;
        s[R * WPR + w] = st;
        pr[R * WPR + w] = cum;
        cum += (int)__popcll(st);
    }
}

// One block per (image, strip, phase): full intra-strip CCL + flags in LDS,
// then coalesced write of the strip's 16384 parent entries.
__global__ __launch_bounds__(NTHR_S) void
k_strip(const u64* __restrict__ fT, const u64* __restrict__ fP,
        const u64* __restrict__ sT, const u64* __restrict__ sP,
        const int* __restrict__ prT, const int* __restrict__ prP,
        int* __restrict__ parentT, int* __restrict__ parentP) {
    __shared__ int lab[SLOTS];
    int bid = blockIdx.x;
    int ph = bid & 1; bid >>= 1;
    int strip = bid & (STRIPS - 1);
    int img = bid >> 5;
    const u64* f = ph ? fP : fT;
    const u64* fB = ph ? fT : fP;   // coverage mask (mistake = fg & !other)
    const u64* s = ph ? sP : sT;
    const int* pr = ph ? prP : prT;
    int* parent = ph ? parentP : parentT;
    const int row0 = img * HH + strip * SROWS;  // chunk-local row index

    for (int i = threadIdx.x; i < SLOTS; i += NTHR_S) lab[i] = i;
    __syncthreads();

    // intra-strip vertical unites (31 row pairs x 16 words)
    for (int task = threadIdx.x; task < (SROWS - 1) * WPR; task += NTHR_S) {
        int r = task >> 4, w = task & 15;
        int w0 = (row0 + r) * WPR + w, w1 = w0 + WPR;
        u64 f0 = f[w0], f1 = f[w1];
        u64 o = f0 & f1;
        if (!o) continue;
        u64 s0 = s[w0], s1 = s[w1];
        int b0 = r * RPR + pr[w0], b1 = (r + 1) * RPR + pr[w1];
        u64 os = o & ~(o << 1);  // one unite per overlap-run
        while (os) {
            int b = __builtin_ctzll(os);
            os &= os - 1;
            uniteL(lab, b0 + runIndexW(s0, b), b1 + runIndexW(s1, b));
        }
    }
    __syncthreads();

    // mistake flags onto local roots (prechecked LDS atomicOr)
    volatile int* vl = lab;
    for (int task = threadIdx.x; task < SROWS * WPR; task += NTHR_S) {
        int r = task >> 4, w = task & 15;
        int wi = (row0 + r) * WPR + w;
        u64 m = f[wi] & ~fB[wi];
        if (!m) continue;
        u64 sw = s[wi];
        int base = r * RPR + pr[wi];
        u64 ms = m & ~(m << 1);
        int last = -1;
        while (ms) {
            int b = __builtin_ctzll(ms);
            ms &= ms - 1;
            int rid = base + runIndexW(sw, b);
            if (rid == last) continue;
            last = rid;
            int rt = findRootL(vl, rid);
            if (!(vl[rt] & FLAGBIT)) atomicOr(&lab[rt], FLAGBIT);
        }
    }
    __syncthreads();

    // compress + coalesced write: root entries carry their flag
    const int gb = row0 * RPR;
    for (int i = threadIdx.x; i < SLOTS; i += NTHR_S) {
        int e = lab[i];
        int rt = e & IDXMASK;
        if (rt != i) rt = findRootL(vl, rt);
        int val = (rt == i) ? ((gb + i) | (e & FLAGBIT)) : (gb + rt);
        parent[gb + i] = val;
    }
}

// Global unions across the 31 strip seams per image (flag-carrying).
__global__ void k_bound(const u64* __restrict__ fT, const u64* __restrict__ fP,
                        const u64* __restrict__ sT, const u64* __restrict__ sP,
                        const int* __restrict__ prT, const int* __restrict__ prP,
                        int* __restrict__ parentT, int* __restrict__ parentP, int nb) {
    int tasks = nb * (STRIPS - 1) * WPR * 2;
    int stride = gridDim.x * blockDim.x;
    for (int id = blockIdx.x * blockDim.x + threadIdx.x; id < tasks; id += stride) {
        int ph = id & 1;
        int t = id >> 1;
        int w = t & 15; t >>= 4;
        int bnd = t % (STRIPS - 1);
        int img = t / (STRIPS - 1);
        int R = img * HH + bnd * SROWS + (SROWS - 1);  // last row of strip bnd
        const u64* f = ph ? fP : fT;
        const u64* s = ph ? sP : sT;
        const int* pr = ph ? prP : prT;
        int* parent = ph ? parentP : parentT;
        int w0 = R * WPR + w, w1 = w0 + WPR;
        u64 f0 = f[w0], f1 = f[w1];
        u64 o = f0 & f1;
        if (!o) continue;
        u64 s0 = s[w0], s1 = s[w1];
        int b0 = R * RPR + pr[w0], b1 = (R + 1) * RPR + pr[w1];
        u64 os = o & ~(o << 1);
        while (os) {
            int b = __builtin_ctzll(os);
            os &= os - 1;
            uniteGF(parent, b0 + runIndexW(s0, b), b1 + runIndexW(s1, b));
        }
    }
}

// Streaming: every entry -> finalroot | rootflag (1-hop lookups in accum).
__global__ void k_compress(int* __restrict__ parentT, int* __restrict__ parentP, int n) {
    int stride = gridDim.x * blockDim.x;
    for (int i = blockIdx.x * blockDim.x + threadIdx.x; i < n; i += stride) {
        int e = parentT[i];
        int r = e & IDXMASK;
        int fl;
        if (r == i) fl = e & FLAGBIT;
        else { r = findRootG(parentT, r); fl = parentT[r] & FLAGBIT; }
        parentT[i] = r | fl;
        e = parentP[i];
        r = e & IDXMASK;
        if (r == i) fl = e & FLAGBIT;
        else { r = findRootG(parentP, r); fl = parentP[r] & FLAGBIT; }
        parentP[i] = r | fl;
    }
}

// Fused loss + weights; crit lookup once per run segment; per-block partials.
__global__ void k_accum(const float* __restrict__ preds, const float* __restrict__ targets,
                        long gbase, int npx4,
                        const u64* __restrict__ fT, const u64* __restrict__ fP,
                        const u64* __restrict__ sT, const u64* __restrict__ sP,
                        const int* __restrict__ prT, const int* __restrict__ prP,
                        const int* __restrict__ parentT, const int* __restrict__ parentP,
                        double* __restrict__ part) {
    int stride = gridDim.x * blockDim.x;
    double local = 0.0;
    const float4* p4 = (const float4*)(preds + gbase);
    const float4* t4 = (const float4*)(targets + gbase);
    for (int i = blockIdx.x * blockDim.x + threadIdx.x; i < npx4; i += stride) {
        float4 pv = p4[i];
        float4 tv = t4[i];
        int px = i << 2;                      // chunk-local pixel index
        int R = px >> 10;                     // chunk-local row
        int wi = R * WPR + ((px >> 6) & 15);
        u64 ft = fT[wi], fp = fP[wi];
        u64 st = sT[wi], sp = sP[wi];
        int baseT = R * RPR + prT[wi];
        int baseP = R * RPR + prP[wi];
        float pa[4] = {pv.x, pv.y, pv.z, pv.w};
        float ta[4] = {tv.x, tv.y, tv.z, tv.w};
        int lastT = -1, lastP = -1;
        float flagT = 0.0f, flagP = 0.0f;
        #pragma unroll
        for (int j = 0; j < 4; ++j) {
            int b = (px & 63) + j;
            float p = pa[j], t = ta[j];
            float loss = fmaxf(p, 0.0f) - p * t + log1pf(__expf(-fabsf(p)));
            float wgt = 0.5f;
            if ((ft >> b) & 1) {
                int rid = baseT + runIndexW(st, b);
                if (rid != lastT) { lastT = rid; flagT = (parentT[rid] & FLAGBIT) ? 0.25f : 0.0f; }
                wgt += flagT;
            }
            if ((fp >> b) & 1) {
                int rid = baseP + runIndexW(sp, b);
                if (rid != lastP) { lastP = rid; flagP = (parentP[rid] & FLAGBIT) ? 0.25f : 0.0f; }
                wgt += flagP;
            }
            local += (double)(wgt * loss);
        }
    }
    #pragma unroll
    for (int off = 32; off > 0; off >>= 1) local += __shfl_down(local, off, 64);
    __shared__ double sh[NTHR / 64];
    int lane = threadIdx.x & 63, wid = threadIdx.x >> 6;
    if (lane == 0) sh[wid] = local;
    __syncthreads();
    if (threadIdx.x == 0) {
        double tot = 0.0;
        #pragma unroll
        for (int w = 0; w < NTHR / 64; ++w) tot += sh[w];
        part[blockIdx.x] += tot;  // zeroed each launch; chunks accumulate serially
    }
}

__global__ void k_final(const double* __restrict__ part, float* __restrict__ out, double inv_n) {
    double v = 0.0;
    for (int i = threadIdx.x; i < NBLK; i += blockDim.x) v += part[i];
    #pragma unroll
    for (int off = 32; off > 0; off >>= 1) v += __shfl_down(v, off, 64);
    __shared__ double sh[NTHR / 64];
    int lane = threadIdx.x & 63, wid = threadIdx.x >> 6;
    if (lane == 0) sh[wid] = v;
    __syncthreads();
    if (threadIdx.x == 0) {
        double tot = 0.0;
        #pragma unroll
        for (int w = 0; w < NTHR / 64; ++w) tot += sh[w];
        out[0] = (float)(tot * inv_n);
    }
}

extern "C" void kernel_launch(void* const* d_in, const int* in_sizes, int n_in,
                              void* d_out, int out_size, void* d_ws, size_t ws_size,
                              hipStream_t stream) {
    const float* preds = (const float*)d_in[0];
    const float* targets = (const float*)d_in[1];
    float* out = (float*)d_out;

    // ws: part | fT fP sT sP | prT prP | parentT parentP   (chunked by image)
    double* part = (double*)d_ws;
    char* base = (char*)d_ws + NBLK * sizeof(double);
    size_t avail = (ws_size > NBLK * sizeof(double)) ? ws_size - NBLK * sizeof(double) : 0;
    const size_t wpi = (size_t)HH * WPR;             // 16384 words per image
    const size_t runs_pi = (size_t)HH * RPR;         // 524288 run slots per image
    const size_t per_img = 4 * wpi * sizeof(u64) + 2 * wpi * sizeof(int)
                         + 2 * runs_pi * sizeof(int);  // ~4.63 MB
    int chunk = (int)(avail / per_img);
    if (chunk < 1) chunk = 1;
    if (chunk > NB_TOTAL) chunk = NB_TOTAL;

    u64* fT = (u64*)base;
    u64* fP = fT + (size_t)chunk * wpi;
    u64* sT = fP + (size_t)chunk * wpi;
    u64* sP = sT + (size_t)chunk * wpi;
    int* prT = (int*)(sP + (size_t)chunk * wpi);
    int* prP = prT + (size_t)chunk * wpi;
    int* parentT = prP + (size_t)chunk * wpi;
    int* parentP = parentT + (size_t)chunk * runs_pi;

    k_zero<<<NBLK / NTHR, NTHR, 0, stream>>>(part);

    for (int b0 = 0; b0 < NB_TOTAL; b0 += chunk) {
        int nb = (b0 + chunk <= NB_TOTAL) ? chunk : (NB_TOTAL - b0);
        int npx = nb * IMGPIX;
        long gbase = (long)b0 * IMGPIX;
        int nrows = nb * HH;
        int nruns = (int)(nb * runs_pi);

        k_mask<<<NBLK, NTHR, 0, stream>>>(preds, targets, gbase, npx, fT, fP);
        k_rows<<<(2 * nrows + NTHR - 1) / NTHR, NTHR, 0, stream>>>(fT, fP, sT, sP,
                                                                   prT, prP, nrows);
        k_strip<<<nb * STRIPS * 2, NTHR_S, 0, stream>>>(fT, fP, sT, sP, prT, prP,
                                                        parentT, parentP);
        k_bound<<<64, NTHR, 0, stream>>>(fT, fP, sT, sP, prT, prP, parentT, parentP, nb);
        k_compress<<<NBLK, NTHR, 0, stream>>>(parentT, parentP, nruns);
        k_accum<<<NBLK, NTHR, 0, stream>>>(preds, targets, gbase, npx >> 2,
                                           fT, fP, sT, sP, prT, prP,
                                           parentT, parentP, part);
    }

    double inv_n = 1.0 / ((double)NB_TOTAL * (double)IMGPIX);
    k_final<<<1, NTHR, 0, stream>>>(part, out, inv_n);
}